// Round 5
// baseline (624.609 us; speedup 1.0000x reference)
//
#include <hip/hip_runtime.h>
#include <hip/hip_bf16.h>
#include <stdint.h>

// Problem constants (from reference)
#define E_EDGES 1048576
#define NN 50000
#define NODE_H 128
#define EDGE_H 64
#define GNN_H 128
#define K1 320  // 2*NODE_H + EDGE_H
#define K2 256  // NODE_H + GNN_H
#define NB 16   // nodes per block in fused kernels

typedef __bf16 bf16_t;
typedef __bf16 bf16x8 __attribute__((ext_vector_type(8)));
typedef float floatx4 __attribute__((ext_vector_type(4)));

// Workspace layout (bytes)
#define OFF_FLAG 0
#define OFF_CNT 256          // int cnt[NN]                              200192
#define OFF_W1T 200448       // bf16 W1^T [128][320]  (v1 path)          81920
#define OFF_W2T 282368       // bf16 W2^T [128][256]                     65536
#define OFF_W1ABT 347904     // bf16 [256][128]: n<128 -> W1a^T else W1b^T
#define OFF_W1CT 413440      // bf16 W1c^T [128][64]                     16384
#define OFF_RP 429824        // int rowptr[NN+1]                        200448
#define OFF_WOFF 630272      // int woff[NN]                            200192
#define OFF_PERM 830464      // uint pk32[E] (v5) -- 4194304 bytes
#define OFF_RC 5024768       // bf16 RC[NN][256]: [0:128]=x@W1a, [128:256]=x@W1b
#define WS_V3 ((size_t)OFF_RC + (size_t)NN * 256 * 2)   // 30624768
#define OFF_PK64 WS_V3                                   // u64 packed[E] (v4)
#define WS_V4 (WS_V3 + (size_t)E_EDGES * 8)              // 39013376
#define OFF_EAS WS_V3                                    // bf16 ea_s[E][64] (v5)
#define WS_V5 (WS_V3 + (size_t)E_EDGES * 128)            // 164842496

__device__ __forceinline__ long load_idx(const void* ei, int is64, long off) {
    return is64 ? (long)((const long long*)ei)[off] : (long)((const int*)ei)[off];
}

#define MFMA(a, b, c) __builtin_amdgcn_mfma_f32_16x16x32_bf16(a, b, c, 0, 0, 0)

// Prep: weight transforms + edge_index dtype probe.
__global__ void prep_kernel(const float* __restrict__ W1, const float* __restrict__ W2,
                            const int* __restrict__ ei32, char* __restrict__ ws) {
    bf16_t* w1t = (bf16_t*)(ws + OFF_W1T);
    bf16_t* w2t = (bf16_t*)(ws + OFF_W2T);
    bf16_t* w1abt = (bf16_t*)(ws + OFF_W1ABT);
    bf16_t* w1ct = (bf16_t*)(ws + OFF_W1CT);
    int tid = blockIdx.x * blockDim.x + threadIdx.x;
    int nt = gridDim.x * blockDim.x;
    for (int i = tid; i < K1 * GNN_H; i += nt) {
        int n = i / K1, k = i - n * K1;
        w1t[i] = (bf16_t)W1[k * GNN_H + n];
    }
    for (int i = tid; i < K2 * GNN_H; i += nt) {
        int n = i / K2, k = i - n * K2;
        w2t[i] = (bf16_t)W2[k * GNN_H + n];
    }
    for (int i = tid; i < 256 * 128; i += nt) {
        int n = i >> 7, k = i & 127;
        int kk = (n < 128) ? k : k + 128;
        w1abt[i] = (bf16_t)W1[kk * GNN_H + (n & 127)];
    }
    for (int i = tid; i < 128 * 64; i += nt) {
        int n = i >> 6, k = i & 63;
        w1ct[i] = (bf16_t)W1[(256 + k) * GNN_H + n];
    }
    if (blockIdx.x == 0) {
        __shared__ int any_nonzero;
        if (threadIdx.x == 0) any_nonzero = 0;
        __syncthreads();
        if (ei32[2 * threadIdx.x + 1] != 0) atomicOr(&any_nonzero, 1);
        __syncthreads();
        if (threadIdx.x == 0) *(int*)(ws + OFF_FLAG) = (any_nonzero == 0) ? 1 : 0;
    }
}

// ---------------- counting sort by col ----------------

__global__ void hist_kernel(const void* __restrict__ ei, const char* __restrict__ ws,
                            int* __restrict__ cnt) {
    int is64 = *(const int*)(ws + OFF_FLAG);
    int e = blockIdx.x * blockDim.x + threadIdx.x;
    if (e < E_EDGES) {
        long c = load_idx(ei, is64, (long)E_EDGES + e);
        atomicAdd(cnt + c, 1);
    }
}

__global__ __launch_bounds__(1024) void scan_kernel(const int* __restrict__ cnt,
                                                    int* __restrict__ rowptr,
                                                    int* __restrict__ woff) {
    __shared__ int part[1024];
    int t = threadIdx.x;
    const int CH = (NN + 1023) / 1024;
    int base = t * CH;
    int n = NN - base;
    if (n < 0) n = 0;
    if (n > CH) n = CH;
    int s = 0;
    for (int i = 0; i < n; ++i) s += cnt[base + i];
    part[t] = s;
    __syncthreads();
    for (int off = 1; off < 1024; off <<= 1) {
        int v = (t >= off) ? part[t - off] : 0;
        __syncthreads();
        part[t] += v;
        __syncthreads();
    }
    int run = part[t] - s;
    for (int i = 0; i < n; ++i) {
        rowptr[base + i] = run;
        woff[base + i] = run;
        run += cnt[base + i];
    }
    if (t == 1023) rowptr[NN] = part[1023];
}

// mode 1: write pk64 {e:20|row:17|nl:4} (v4).
// mode 2: write pk32 {row:17|nl:4} + permute ea -> bf16 ea_s[pos] (v5).
__global__ void scatter_kernel(const void* __restrict__ ei, const float* __restrict__ ea,
                               char* __restrict__ ws, int* __restrict__ woff, int mode) {
    int is64 = *(const int*)(ws + OFF_FLAG);
    int e = blockIdx.x * blockDim.x + threadIdx.x;
    if (e >= E_EDGES) return;
    long row = load_idx(ei, is64, e);
    long col = load_idx(ei, is64, (long)E_EDGES + e);
    int pos = atomicAdd(woff + col, 1);
    if (mode == 2) {
        ((unsigned*)(ws + OFF_PERM))[pos] =
            (unsigned)row | (((unsigned)col & 15u) << 17);
        const floatx4* src = (const floatx4*)(ea + (size_t)e * EDGE_H);
        bf16_t* dst = (bf16_t*)(ws + OFF_EAS) + (size_t)pos * EDGE_H;
#pragma unroll
        for (int c = 0; c < 8; ++c) {
            floatx4 f0 = src[2 * c];
            floatx4 f1 = src[2 * c + 1];
            bf16x8 v;
#pragma unroll
            for (int j = 0; j < 4; ++j) {
                v[j] = (bf16_t)f0[j];
                v[j + 4] = (bf16_t)f1[j];
            }
            *(bf16x8*)(dst + c * 8) = v;
        }
    } else {
        ((unsigned long long*)(ws + OFF_PK64))[pos] =
            (unsigned long long)e | ((unsigned long long)(unsigned)row << 20) |
            ((unsigned long long)((unsigned)col & 15u) << 37);
    }
}

// ---------------- RC = x @ [W1a | W1b] (bf16 out) ----------------

__global__ __launch_bounds__(256) void rc_kernel(const float* __restrict__ x,
                                                 char* __restrict__ ws) {
    const bf16_t* w1abt = (const bf16_t*)(ws + OFF_W1ABT);
    bf16_t* rc = (bf16_t*)(ws + OFF_RC);
    int lane = threadIdx.x & 63;
    int w = threadIdx.x >> 6;
    int li = lane & 15;
    int h = lane >> 4;
    int m0 = blockIdx.x * 16;

    bf16x8 bf[4][4];
#pragma unroll
    for (int t = 0; t < 4; ++t)
#pragma unroll
        for (int ks = 0; ks < 4; ++ks)
            bf[t][ks] = *(const bf16x8*)(w1abt + (w * 64 + t * 16 + li) * 128 + ks * 32 + h * 8);

    const float* px = x + (long)(m0 + li) * NODE_H + h * 8;
    floatx4 acc[4] = {{0.f, 0.f, 0.f, 0.f}, {0.f, 0.f, 0.f, 0.f},
                      {0.f, 0.f, 0.f, 0.f}, {0.f, 0.f, 0.f, 0.f}};
#pragma unroll
    for (int ks = 0; ks < 4; ++ks) {
        floatx4 f0 = *(const floatx4*)(px + ks * 32);
        floatx4 f1 = *(const floatx4*)(px + ks * 32 + 4);
        bf16x8 a;
#pragma unroll
        for (int j = 0; j < 4; ++j) {
            a[j] = (bf16_t)f0[j];
            a[j + 4] = (bf16_t)f1[j];
        }
#pragma unroll
        for (int t = 0; t < 4; ++t) acc[t] = MFMA(a, bf[t][ks], acc[t]);
    }
#pragma unroll
    for (int t = 0; t < 4; ++t)
#pragma unroll
        for (int r = 0; r < 4; ++r)
            rc[(long)(m0 + 4 * h + r) * 256 + w * 64 + t * 16 + li] = (bf16_t)acc[t][r];
}

// ---------------- shared node-MLP epilogue ----------------
__device__ __forceinline__ void node_mlp(const float* __restrict__ x,
                                         const float* __restrict__ b2,
                                         const char* __restrict__ ws,
                                         const float (*agg)[132], const int* rowptr,
                                         float* __restrict__ out, int v0, int li, int h,
                                         int n0) {
    const bf16_t* w2t = (const bf16_t*)(ws + OFF_W2T);
    bf16x8 bfr2[2][8];
#pragma unroll
    for (int t = 0; t < 2; ++t)
#pragma unroll
        for (int ks = 0; ks < 8; ++ks)
            bfr2[t][ks] = *(const bf16x8*)(w2t + (long)(n0 + t * 16 + li) * K2 + ks * 32 + h * 8);
    float nb0 = b2[n0 + li];
    float nb1 = b2[n0 + 16 + li];

    int node = v0 + li;
    float rcn = 1.0f / fmaxf((float)(rowptr[node + 1] - rowptr[node]), 1.0f);
    const float* px = x + (long)node * NODE_H + h * 8;
    floatx4 acc0 = {0.f, 0.f, 0.f, 0.f};
    floatx4 acc1 = {0.f, 0.f, 0.f, 0.f};
#pragma unroll
    for (int ks = 0; ks < 8; ++ks) {
        floatx4 f0, f1;
        if (ks < 4) {
            f0 = *(const floatx4*)(px + ks * 32);
            f1 = *(const floatx4*)(px + ks * 32 + 4);
        } else {
            const float* sa = &agg[li][(ks - 4) * 32 + h * 8];
            f0 = *(const floatx4*)(sa);
            f1 = *(const floatx4*)(sa + 4);
            f0 *= rcn;
            f1 *= rcn;
        }
        bf16x8 a;
#pragma unroll
        for (int j = 0; j < 4; ++j) {
            a[j] = (bf16_t)f0[j];
            a[j + 4] = (bf16_t)f1[j];
        }
        acc0 = MFMA(a, bfr2[0][ks], acc0);
        acc1 = MFMA(a, bfr2[1][ks], acc1);
    }
#pragma unroll
    for (int r = 0; r < 4; ++r) {
        long ir = v0 + h * 4 + r;
        out[ir * GNN_H + n0 + li] = fmaxf(acc0[r] + nb0, 0.f);
        out[ir * GNN_H + n0 + 16 + li] = fmaxf(acc1[r] + nb1, 0.f);
    }
}

// ---------------- v5 fused: fully sequential streams + L2 R-gather ----------------
__global__ __launch_bounds__(256) void fused_v5(
    const float* __restrict__ x, const float* __restrict__ b1,
    const float* __restrict__ b2, const char* __restrict__ ws,
    float* __restrict__ out) {
    const bf16_t* w1ct = (const bf16_t*)(ws + OFF_W1CT);
    const bf16_t* rc = (const bf16_t*)(ws + OFF_RC);
    const int* rowptr = (const int*)(ws + OFF_RP);
    const unsigned* pk32 = (const unsigned*)(ws + OFF_PERM);
    const bf16_t* eas = (const bf16_t*)(ws + OFF_EAS);

    __shared__ float agg[NB][132];
    __shared__ float cl[NB][128];

    int lane = threadIdx.x & 63;
    int w = threadIdx.x >> 6;
    int li = lane & 15;
    int h = lane >> 4;
    int n0 = w * 32;
    int v0 = blockIdx.x * NB;

    for (int i = threadIdx.x; i < NB * 132; i += 256) ((float*)agg)[i] = 0.f;
    {   // stage C-part rows for the block's 16 nodes
        int j = threadIdx.x >> 4;
        int c0 = (threadIdx.x & 15) * 8;
        bf16x8 v = *(const bf16x8*)(rc + (long)(v0 + j) * 256 + 128 + c0);
#pragma unroll
        for (int q = 0; q < 8; ++q) cl[j][c0 + q] = (float)v[q];
    }

    bf16x8 bc00 = *(const bf16x8*)(w1ct + (n0 + li) * 64 + h * 8);
    bf16x8 bc01 = *(const bf16x8*)(w1ct + (n0 + li) * 64 + 32 + h * 8);
    bf16x8 bc10 = *(const bf16x8*)(w1ct + (n0 + 16 + li) * 64 + h * 8);
    bf16x8 bc11 = *(const bf16x8*)(w1ct + (n0 + 16 + li) * 64 + 32 + h * 8);
    float bias0 = b1[n0 + li];
    float bias1 = b1[n0 + 16 + li];

    int e_beg = rowptr[v0];
    int e_end = rowptr[v0 + NB];
    __syncthreads();

    if (e_beg < e_end) {
        int ntile = (e_end - e_beg + 15) >> 4;
        auto cl4 = [&](int p) { return p < e_end ? p : e_end - 1; };

        // prologue: tile0 pk + ea + R; tile1 pk in flight
        unsigned pkc[4], pkn[4];
#pragma unroll
        for (int r = 0; r < 4; ++r) pkc[r] = pk32[cl4(e_beg + h * 4 + r)];
        const bf16_t* pe = eas + (size_t)cl4(e_beg + li) * EDGE_H;
        bf16x8 eac0 = *(const bf16x8*)(pe + h * 8);
        bf16x8 eac1 = *(const bf16x8*)(pe + 32 + h * 8);
        bf16_t Rc0[4], Rc1[4];
#pragma unroll
        for (int r = 0; r < 4; ++r) {
            const bf16_t* pr = rc + (size_t)(pkc[r] & 0x1FFFFu) * 256 + n0 + li;
            Rc0[r] = pr[0];
            Rc1[r] = pr[16];
        }
#pragma unroll
        for (int r = 0; r < 4; ++r)
            pkn[r] = pk32[cl4(e_beg + 16 + h * 4 + r)];

        for (int t = 0; t < ntile; ++t) {
            int base = e_beg + (t << 4);
            // ---- issue next-tile loads (consumed at t+1) ----
            bf16_t Rn0[4], Rn1[4];
#pragma unroll
            for (int r = 0; r < 4; ++r) {
                const bf16_t* pr = rc + (size_t)(pkn[r] & 0x1FFFFu) * 256 + n0 + li;
                Rn0[r] = pr[0];
                Rn1[r] = pr[16];
            }
            const bf16_t* pen = eas + (size_t)cl4(base + 16 + li) * EDGE_H;
            bf16x8 ean0 = *(const bf16x8*)(pen + h * 8);
            bf16x8 ean1 = *(const bf16x8*)(pen + 32 + h * 8);
            unsigned pk2[4];
#pragma unroll
            for (int r = 0; r < 4; ++r)
                pk2[r] = pk32[cl4(base + 32 + h * 4 + r)];

            // ---- compute tile t ----
            floatx4 acc0 = {0.f, 0.f, 0.f, 0.f};
            floatx4 acc1 = {0.f, 0.f, 0.f, 0.f};
            acc0 = MFMA(eac0, bc00, acc0);
            acc0 = MFMA(eac1, bc01, acc0);
            acc1 = MFMA(eac0, bc10, acc1);
            acc1 = MFMA(eac1, bc11, acc1);

            float m0v[4], m1v[4];
            int nlr[4], valid[4];
#pragma unroll
            for (int r = 0; r < 4; ++r) {
                nlr[r] = (int)((pkc[r] >> 17) & 15u);
                valid[r] = (base + h * 4 + r) < e_end;
                m0v[r] = fmaxf(acc0[r] + (float)Rc0[r] + cl[nlr[r]][n0 + li] + bias0, 0.f);
                m1v[r] = fmaxf(acc1[r] + (float)Rc1[r] + cl[nlr[r]][n0 + 16 + li] + bias1, 0.f);
            }
            if (valid[3] && nlr[0] == nlr[1] && nlr[1] == nlr[2] && nlr[2] == nlr[3]) {
                atomicAdd(&agg[nlr[0]][n0 + li], m0v[0] + m0v[1] + m0v[2] + m0v[3]);
                atomicAdd(&agg[nlr[0]][n0 + 16 + li], m1v[0] + m1v[1] + m1v[2] + m1v[3]);
            } else {
#pragma unroll
                for (int r = 0; r < 4; ++r) {
                    if (valid[r]) {
                        atomicAdd(&agg[nlr[r]][n0 + li], m0v[r]);
                        atomicAdd(&agg[nlr[r]][n0 + 16 + li], m1v[r]);
                    }
                }
            }
            // ---- rotate ----
#pragma unroll
            for (int r = 0; r < 4; ++r) {
                pkc[r] = pkn[r];
                pkn[r] = pk2[r];
                Rc0[r] = Rn0[r];
                Rc1[r] = Rn1[r];
            }
            eac0 = ean0;
            eac1 = ean1;
        }
    }
    __syncthreads();
    node_mlp(x, b2, ws, agg, rowptr, out, v0, li, h, n0);
}

// ---------------- v4 fused (fallback, proven) ----------------
__global__ __launch_bounds__(256) void fused_v4(
    const float* __restrict__ x, const float* __restrict__ ea,
    const float* __restrict__ b1, const float* __restrict__ b2,
    const char* __restrict__ ws, float* __restrict__ out) {
    const bf16_t* w1ct = (const bf16_t*)(ws + OFF_W1CT);
    const bf16_t* rc = (const bf16_t*)(ws + OFF_RC);
    const int* rowptr = (const int*)(ws + OFF_RP);
    const unsigned long long* pk64 = (const unsigned long long*)(ws + OFF_PK64);

    __shared__ float agg[NB][132];
    __shared__ float cl[NB][128];

    int lane = threadIdx.x & 63;
    int w = threadIdx.x >> 6;
    int li = lane & 15;
    int h = lane >> 4;
    int n0 = w * 32;
    int v0 = blockIdx.x * NB;

    for (int i = threadIdx.x; i < NB * 132; i += 256) ((float*)agg)[i] = 0.f;
    {
        int j = threadIdx.x >> 4;
        int c0 = (threadIdx.x & 15) * 8;
        bf16x8 v = *(const bf16x8*)(rc + (long)(v0 + j) * 256 + 128 + c0);
#pragma unroll
        for (int q = 0; q < 8; ++q) cl[j][c0 + q] = (float)v[q];
    }

    bf16x8 bc00 = *(const bf16x8*)(w1ct + (n0 + li) * 64 + h * 8);
    bf16x8 bc01 = *(const bf16x8*)(w1ct + (n0 + li) * 64 + 32 + h * 8);
    bf16x8 bc10 = *(const bf16x8*)(w1ct + (n0 + 16 + li) * 64 + h * 8);
    bf16x8 bc11 = *(const bf16x8*)(w1ct + (n0 + 16 + li) * 64 + 32 + h * 8);
    float bias0 = b1[n0 + li];
    float bias1 = b1[n0 + 16 + li];

    int e_beg = rowptr[v0];
    int e_end = rowptr[v0 + NB];
    __syncthreads();

    if (e_beg < e_end) {
        int ntile = (e_end - e_beg + 15) >> 4;
        auto posOf = [&](int t) { int p = e_beg + (t << 4) + li; return p < e_end ? p : e_end - 1; };

        unsigned long long pkA = pk64[posOf(0)];
        unsigned long long pkB = pk64[posOf(ntile > 1 ? 1 : 0)];
        unsigned eA = (unsigned)pkA & 0xFFFFFu;
        const float* peA = ea + (size_t)eA * EDGE_H + h * 8;
        floatx4 eaA00 = *(const floatx4*)peA;
        floatx4 eaA01 = *(const floatx4*)(peA + 4);
        floatx4 eaA10 = *(const floatx4*)(peA + 32);
        floatx4 eaA11 = *(const floatx4*)(peA + 36);
        int rowA = (int)((pkA >> 20) & 0x1FFFFu);
        int nlA = (int)((pkA >> 37) & 15u);
        bf16_t RA0[4], RA1[4];
        int nlrA[4];
#pragma unroll
        for (int r = 0; r < 4; ++r) {
            int rr = __shfl(rowA, h * 4 + r, 64);
            nlrA[r] = __shfl(nlA, h * 4 + r, 64);
            const bf16_t* pr = rc + (size_t)rr * 256 + n0 + li;
            RA0[r] = pr[0];
            RA1[r] = pr[16];
        }

        for (int t = 0; t < ntile; ++t) {
            unsigned long long pkC = pk64[posOf(t + 2 < ntile ? t + 2 : ntile - 1)];
            unsigned eB = (unsigned)pkB & 0xFFFFFu;
            const float* peB = ea + (size_t)eB * EDGE_H + h * 8;
            floatx4 eaB00 = *(const floatx4*)peB;
            floatx4 eaB01 = *(const floatx4*)(peB + 4);
            floatx4 eaB10 = *(const floatx4*)(peB + 32);
            floatx4 eaB11 = *(const floatx4*)(peB + 36);
            int rowB = (int)((pkB >> 20) & 0x1FFFFu);
            int nlB = (int)((pkB >> 37) & 15u);
            bf16_t RB0[4], RB1[4];
            int nlrB[4];
#pragma unroll
            for (int r = 0; r < 4; ++r) {
                int rr = __shfl(rowB, h * 4 + r, 64);
                nlrB[r] = __shfl(nlB, h * 4 + r, 64);
                const bf16_t* pr = rc + (size_t)rr * 256 + n0 + li;
                RB0[r] = pr[0];
                RB1[r] = pr[16];
            }

            bf16x8 a0, a1;
#pragma unroll
            for (int j = 0; j < 4; ++j) {
                a0[j] = (bf16_t)eaA00[j];
                a0[j + 4] = (bf16_t)eaA01[j];
                a1[j] = (bf16_t)eaA10[j];
                a1[j + 4] = (bf16_t)eaA11[j];
            }
            floatx4 acc0 = {0.f, 0.f, 0.f, 0.f};
            floatx4 acc1 = {0.f, 0.f, 0.f, 0.f};
            acc0 = MFMA(a0, bc00, acc0);
            acc0 = MFMA(a1, bc01, acc0);
            acc1 = MFMA(a0, bc10, acc1);
            acc1 = MFMA(a1, bc11, acc1);

            int base = e_beg + (t << 4);
            float m0v[4], m1v[4];
            int valid[4];
#pragma unroll
            for (int r = 0; r < 4; ++r) {
                valid[r] = (base + h * 4 + r) < e_end;
                m0v[r] = fmaxf(acc0[r] + (float)RA0[r] + cl[nlrA[r]][n0 + li] + bias0, 0.f);
                m1v[r] = fmaxf(acc1[r] + (float)RA1[r] + cl[nlrA[r]][n0 + 16 + li] + bias1, 0.f);
            }
            if (valid[3] && nlrA[0] == nlrA[1] && nlrA[1] == nlrA[2] && nlrA[2] == nlrA[3]) {
                atomicAdd(&agg[nlrA[0]][n0 + li], m0v[0] + m0v[1] + m0v[2] + m0v[3]);
                atomicAdd(&agg[nlrA[0]][n0 + 16 + li], m1v[0] + m1v[1] + m1v[2] + m1v[3]);
            } else {
#pragma unroll
                for (int r = 0; r < 4; ++r) {
                    if (valid[r]) {
                        atomicAdd(&agg[nlrA[r]][n0 + li], m0v[r]);
                        atomicAdd(&agg[nlrA[r]][n0 + 16 + li], m1v[r]);
                    }
                }
            }
            pkA = pkB;
            pkB = pkC;
            eaA00 = eaB00; eaA01 = eaB01; eaA10 = eaB10; eaA11 = eaB11;
#pragma unroll
            for (int r = 0; r < 4; ++r) {
                RA0[r] = RB0[r];
                RA1[r] = RB1[r];
                nlrA[r] = nlrB[r];
            }
        }
    }
    __syncthreads();
    node_mlp(x, b2, ws, agg, rowptr, out, v0, li, h, n0);
}

// ---------------- v1 fallback (tiny ws; s == out in-place) ----------------

__global__ void count_kernel(const void* __restrict__ ei, const char* __restrict__ ws,
                             float* __restrict__ cnt) {
    int is64 = *(const int*)(ws + OFF_FLAG);
    int e = blockIdx.x * blockDim.x + threadIdx.x;
    if (e < E_EDGES) {
        long c = load_idx(ei, is64, (long)E_EDGES + e);
        atomicAdd(cnt + c, 1.0f);
    }
}

__global__ __launch_bounds__(256) void edge_kernel(
    const float* __restrict__ x, const void* __restrict__ ei,
    const float* __restrict__ ea, const float* __restrict__ b1,
    const char* __restrict__ ws, float* __restrict__ s) {
    const bf16_t* w1t = (const bf16_t*)(ws + OFF_W1T);
    int is64 = *(const int*)(ws + OFF_FLAG);
    int lane = threadIdx.x & 63;
    int w = threadIdx.x >> 6;
    int li = lane & 15;
    int h = lane >> 4;
    int n0 = w * 32;

    bf16x8 bf[2][10];
#pragma unroll
    for (int t = 0; t < 2; ++t)
#pragma unroll
        for (int ks = 0; ks < 10; ++ks)
            bf[t][ks] = *(const bf16x8*)(w1t + (long)(n0 + t * 16 + li) * K1 + ks * 32 + h * 8);
    float bias0 = b1[n0 + li];
    float bias1 = b1[n0 + 16 + li];

    const int ntiles = E_EDGES / 16;
    for (int tile = blockIdx.x; tile < ntiles; tile += gridDim.x) {
        int m0 = tile * 16;
        int e = m0 + li;
        long rowi = load_idx(ei, is64, e);
        long coli = load_idx(ei, is64, (long)E_EDGES + e);
        const float* pr = x + rowi * NODE_H + h * 8;
        const float* pc = x + coli * NODE_H + h * 8;
        const float* pe = ea + (long)e * EDGE_H + h * 8;
        floatx4 acc0 = {0.f, 0.f, 0.f, 0.f};
        floatx4 acc1 = {0.f, 0.f, 0.f, 0.f};
#pragma unroll
        for (int ks = 0; ks < 10; ++ks) {
            const float* src = (ks < 4) ? (pr + ks * 32) : (ks < 8) ? (pc + (ks - 4) * 32)
                                                                    : (pe + (ks - 8) * 32);
            floatx4 f0 = *(const floatx4*)(src);
            floatx4 f1 = *(const floatx4*)(src + 4);
            bf16x8 a;
#pragma unroll
            for (int j = 0; j < 4; ++j) {
                a[j] = (bf16_t)f0[j];
                a[j + 4] = (bf16_t)f1[j];
            }
            acc0 = MFMA(a, bf[0][ks], acc0);
            acc1 = MFMA(a, bf[1][ks], acc1);
        }
        long cols[4];
#pragma unroll
        for (int r = 0; r < 4; ++r)
            cols[r] = load_idx(ei, is64, (long)E_EDGES + m0 + h * 4 + r);
#pragma unroll
        for (int r = 0; r < 4; ++r) {
            float v0 = fmaxf(acc0[r] + bias0, 0.f);
            float v1 = fmaxf(acc1[r] + bias1, 0.f);
            atomicAdd(s + cols[r] * GNN_H + n0 + li, v0);
            atomicAdd(s + cols[r] * GNN_H + n0 + 16 + li, v1);
        }
    }
}

__global__ __launch_bounds__(256) void node_kernel(
    const float* __restrict__ x, const float* __restrict__ b2,
    const char* __restrict__ ws, const float* __restrict__ cnt,
    const float* __restrict__ s, float* __restrict__ out) {
    const bf16_t* w2t = (const bf16_t*)(ws + OFF_W2T);
    int lane = threadIdx.x & 63;
    int w = threadIdx.x >> 6;
    int li = lane & 15;
    int h = lane >> 4;
    int n0 = w * 32;

    bf16x8 bf[2][8];
#pragma unroll
    for (int t = 0; t < 2; ++t)
#pragma unroll
        for (int ks = 0; ks < 8; ++ks)
            bf[t][ks] = *(const bf16x8*)(w2t + (long)(n0 + t * 16 + li) * K2 + ks * 32 + h * 8);
    float bias0 = b2[n0 + li];
    float bias1 = b2[n0 + 16 + li];

    int m0 = blockIdx.x * 16;
    int i = m0 + li;
    float rcn = 1.0f / fmaxf(cnt[i], 1.0f);
    const float* px = x + (long)i * NODE_H + h * 8;
    const float* ps = s + (long)i * GNN_H + h * 8;
    floatx4 acc0 = {0.f, 0.f, 0.f, 0.f};
    floatx4 acc1 = {0.f, 0.f, 0.f, 0.f};
#pragma unroll
    for (int ks = 0; ks < 8; ++ks) {
        const float* src = (ks < 4) ? (px + ks * 32) : (ps + (ks - 4) * 32);
        floatx4 f0 = *(const floatx4*)(src);
        floatx4 f1 = *(const floatx4*)(src + 4);
        if (ks >= 4) {
            f0 *= rcn;
            f1 *= rcn;
        }
        bf16x8 a;
#pragma unroll
        for (int j = 0; j < 4; ++j) {
            a[j] = (bf16_t)f0[j];
            a[j + 4] = (bf16_t)f1[j];
        }
        acc0 = MFMA(a, bf[0][ks], acc0);
        acc1 = MFMA(a, bf[1][ks], acc1);
    }
    __syncthreads();  // s == out in-place: all reads done before stores
#pragma unroll
    for (int r = 0; r < 4; ++r) {
        long ir = m0 + h * 4 + r;
        out[ir * GNN_H + n0 + li] = fmaxf(acc0[r] + bias0, 0.f);
        out[ir * GNN_H + n0 + 16 + li] = fmaxf(acc1[r] + bias1, 0.f);
    }
}

extern "C" void kernel_launch(void* const* d_in, const int* in_sizes, int n_in,
                              void* d_out, int out_size, void* d_ws, size_t ws_size,
                              hipStream_t stream) {
    const float* x = (const float*)d_in[0];
    const void* ei = d_in[1];
    const float* ea = (const float*)d_in[2];
    const float* W1 = (const float*)d_in[3];
    const float* b1 = (const float*)d_in[4];
    const float* W2 = (const float*)d_in[5];
    const float* b2 = (const float*)d_in[6];
    float* out = (float*)d_out;
    char* ws = (char*)d_ws;

    prep_kernel<<<32, 256, 0, stream>>>(W1, W2, (const int*)ei, ws);

    if (ws_size >= WS_V4) {
        int* cnt = (int*)(ws + OFF_CNT);
        int mode = (ws_size >= WS_V5) ? 2 : 1;
        hipMemsetAsync(cnt, 0, NN * 4, stream);
        hist_kernel<<<E_EDGES / 256, 256, 0, stream>>>(ei, ws, cnt);
        scan_kernel<<<1, 1024, 0, stream>>>(cnt, (int*)(ws + OFF_RP), (int*)(ws + OFF_WOFF));
        scatter_kernel<<<E_EDGES / 256, 256, 0, stream>>>(ei, ea, ws, (int*)(ws + OFF_WOFF), mode);
        rc_kernel<<<NN / 16, 256, 0, stream>>>(x, ws);
        if (mode == 2)
            fused_v5<<<NN / NB, 256, 0, stream>>>(x, b1, b2, ws, out);
        else
            fused_v4<<<NN / NB, 256, 0, stream>>>(x, ea, b1, b2, ws, out);
    } else {
        float* cntf = (float*)(ws + OFF_CNT);
        hipMemsetAsync(cntf, 0, NN * 4, stream);
        hipMemsetAsync(out, 0, (size_t)NN * GNN_H * 4, stream);
        count_kernel<<<E_EDGES / 256, 256, 0, stream>>>(ei, ws, cntf);
        edge_kernel<<<4096, 256, 0, stream>>>(x, ei, ea, b1, ws, out);
        node_kernel<<<NN / 16, 256, 0, stream>>>(x, b2, ws, cntf, out, out);
    }
}

// Round 6
// 574.676 us; speedup vs baseline: 1.0869x; 1.0869x over previous
//
#include <hip/hip_runtime.h>
#include <hip/hip_bf16.h>
#include <stdint.h>

// Problem constants (from reference)
#define E_EDGES 1048576
#define NN 50000
#define NODE_H 128
#define EDGE_H 64
#define GNN_H 128
#define K1 320  // 2*NODE_H + EDGE_H
#define K2 256  // NODE_H + GNN_H
#define NB 16   // nodes per block in fused kernel

typedef __bf16 bf16_t;
typedef __bf16 bf16x8 __attribute__((ext_vector_type(8)));
typedef float floatx4 __attribute__((ext_vector_type(4)));

// Workspace layout (bytes)
#define OFF_FLAG 0
#define OFF_CNT 256          // int cnt[NN]
#define OFF_W1T 200448       // bf16 W1^T [128][320]  (v1 path)
#define OFF_W2T 282368       // bf16 W2^T [128][256]
#define OFF_W1ABT 347904     // bf16 [256][128]
#define OFF_W1CT 413440      // bf16 W1c^T [128][64]
#define OFF_RP 429824        // int rowptr[NN+1]
#define OFF_WOFF 630272      // int woff[NN]
#define OFF_PERM 830464      // u32 pk32[E] = row | (nl<<17)
#define OFF_RC 5024768       // bf16 RC[NN][256]
#define OFF_EIDX (OFF_RC + NN * 256 * 2)        // 30624768: u32 eidx[E]
#define WS_V6 ((size_t)OFF_EIDX + (size_t)E_EDGES * 4)  // ~34.8 MB

__device__ __forceinline__ long load_idx(const void* ei, int is64, long off) {
    return is64 ? (long)((const long long*)ei)[off] : (long)((const int*)ei)[off];
}

#define MFMA(a, b, c) __builtin_amdgcn_mfma_f32_16x16x32_bf16(a, b, c, 0, 0, 0)

// ======================= fast path (ws >= WS_V6) =======================

// K1: weight transforms + histogram (per-block dtype probe, no flag dep).
__global__ __launch_bounds__(256) void prep_hist(const float* __restrict__ W1,
                                                 const float* __restrict__ W2,
                                                 const int* __restrict__ ei32,
                                                 char* __restrict__ ws,
                                                 int* __restrict__ cnt) {
    __shared__ int nz;
    int tid = threadIdx.x;
    int gid = blockIdx.x * 256 + tid;  // < 524288 < E
    if (tid == 0) nz = 0;
    __syncthreads();
    if (ei32[2 * gid + 1] != 0) atomicOr(&nz, 1);
    __syncthreads();
    int is64 = (nz == 0);

    bf16_t* w1t = (bf16_t*)(ws + OFF_W1T);
    bf16_t* w2t = (bf16_t*)(ws + OFF_W2T);
    bf16_t* w1abt = (bf16_t*)(ws + OFF_W1ABT);
    bf16_t* w1ct = (bf16_t*)(ws + OFF_W1CT);
    if (gid < K1 * GNN_H) {
        int n = gid / K1, k = gid - n * K1;
        w1t[gid] = (bf16_t)W1[k * GNN_H + n];
    }
    if (gid < K2 * GNN_H) {
        int n = gid / K2, k = gid - n * K2;
        w2t[gid] = (bf16_t)W2[k * GNN_H + n];
    }
    if (gid < 256 * 128) {
        int n = gid >> 7, k = gid & 127;
        int kk = (n < 128) ? k : k + 128;
        w1abt[gid] = (bf16_t)W1[kk * GNN_H + (n & 127)];
    }
    if (gid < 128 * 64) {
        int n = gid >> 6, k = gid & 63;
        w1ct[gid] = (bf16_t)W1[(256 + k) * GNN_H + n];
    }
    if (gid == 0) *(int*)(ws + OFF_FLAG) = is64;

    const long long* e64 = (const long long*)ei32;
    for (int e = gid; e < E_EDGES; e += 2048 * 256) {
        int col = is64 ? (int)e64[E_EDGES + e] : ei32[E_EDGES + e];
        atomicAdd(cnt + col, 1);
    }
}

__global__ __launch_bounds__(1024) void scan_kernel(const int* __restrict__ cnt,
                                                    int* __restrict__ rowptr,
                                                    int* __restrict__ woff) {
    __shared__ int part[1024];
    int t = threadIdx.x;
    const int CH = (NN + 1023) / 1024;
    int base = t * CH;
    int n = NN - base;
    if (n < 0) n = 0;
    if (n > CH) n = CH;
    int s = 0;
    for (int i = 0; i < n; ++i) s += cnt[base + i];
    part[t] = s;
    __syncthreads();
    for (int off = 1; off < 1024; off <<= 1) {
        int v = (t >= off) ? part[t - off] : 0;
        __syncthreads();
        part[t] += v;
        __syncthreads();
    }
    int run = part[t] - s;
    for (int i = 0; i < n; ++i) {
        rowptr[base + i] = run;
        woff[base + i] = run;
        run += cnt[base + i];
    }
    if (t == 1023) rowptr[NN] = part[1023];
}

// K3 fat kernel: blocks [0,4096) scatter pk32+eidx; blocks [4096,..) compute RC.
__global__ __launch_bounds__(256) void scatrc_kernel(const int* __restrict__ ei32,
                                                     const float* __restrict__ x,
                                                     char* __restrict__ ws,
                                                     int* __restrict__ woff) {
    if (blockIdx.x < E_EDGES / 256) {
        __shared__ int nz;
        int tid = threadIdx.x;
        int e = blockIdx.x * 256 + tid;
        if (tid == 0) nz = 0;
        __syncthreads();
        if (ei32[2 * e + 1] != 0) atomicOr(&nz, 1);
        __syncthreads();
        int is64 = (nz == 0);
        const long long* e64 = (const long long*)ei32;
        int row = is64 ? (int)e64[e] : ei32[e];
        int col = is64 ? (int)e64[E_EDGES + e] : ei32[E_EDGES + e];
        int pos = atomicAdd(woff + col, 1);
        ((unsigned*)(ws + OFF_PERM))[pos] = (unsigned)row | (((unsigned)col & 15u) << 17);
        ((unsigned*)(ws + OFF_EIDX))[pos] = (unsigned)e;
    } else {
        // RC = x @ [W1a | W1b] -> bf16 [NN][256]
        const bf16_t* w1abt = (const bf16_t*)(ws + OFF_W1ABT);
        bf16_t* rc = (bf16_t*)(ws + OFF_RC);
        int lane = threadIdx.x & 63;
        int w = threadIdx.x >> 6;
        int li = lane & 15;
        int h = lane >> 4;
        int m0 = (blockIdx.x - E_EDGES / 256) * 16;

        bf16x8 bf[4][4];
#pragma unroll
        for (int t = 0; t < 4; ++t)
#pragma unroll
            for (int ks = 0; ks < 4; ++ks)
                bf[t][ks] = *(const bf16x8*)(w1abt + (w * 64 + t * 16 + li) * 128 + ks * 32 + h * 8);

        const float* px = x + (long)(m0 + li) * NODE_H + h * 8;
        floatx4 acc[4] = {{0.f, 0.f, 0.f, 0.f}, {0.f, 0.f, 0.f, 0.f},
                          {0.f, 0.f, 0.f, 0.f}, {0.f, 0.f, 0.f, 0.f}};
#pragma unroll
        for (int ks = 0; ks < 4; ++ks) {
            floatx4 f0 = *(const floatx4*)(px + ks * 32);
            floatx4 f1 = *(const floatx4*)(px + ks * 32 + 4);
            bf16x8 a;
#pragma unroll
            for (int j = 0; j < 4; ++j) {
                a[j] = (bf16_t)f0[j];
                a[j + 4] = (bf16_t)f1[j];
            }
#pragma unroll
            for (int t = 0; t < 4; ++t) acc[t] = MFMA(a, bf[t][ks], acc[t]);
        }
#pragma unroll
        for (int t = 0; t < 4; ++t)
#pragma unroll
            for (int r = 0; r < 4; ++r)
                rc[(long)(m0 + 4 * h + r) * 256 + w * 64 + t * 16 + li] = (bf16_t)acc[t][r];
    }
}

// shared node-MLP epilogue
__device__ __forceinline__ void node_mlp(const float* __restrict__ x,
                                         const float* __restrict__ b2,
                                         const char* __restrict__ ws,
                                         const float (*agg)[132], const int* rowptr,
                                         float* __restrict__ out, int v0, int li, int h,
                                         int n0) {
    const bf16_t* w2t = (const bf16_t*)(ws + OFF_W2T);
    bf16x8 bfr2[2][8];
#pragma unroll
    for (int t = 0; t < 2; ++t)
#pragma unroll
        for (int ks = 0; ks < 8; ++ks)
            bfr2[t][ks] = *(const bf16x8*)(w2t + (long)(n0 + t * 16 + li) * K2 + ks * 32 + h * 8);
    float nb0 = b2[n0 + li];
    float nb1 = b2[n0 + 16 + li];

    int node = v0 + li;
    float rcn = 1.0f / fmaxf((float)(rowptr[node + 1] - rowptr[node]), 1.0f);
    const float* px = x + (long)node * NODE_H + h * 8;
    floatx4 acc0 = {0.f, 0.f, 0.f, 0.f};
    floatx4 acc1 = {0.f, 0.f, 0.f, 0.f};
#pragma unroll
    for (int ks = 0; ks < 8; ++ks) {
        floatx4 f0, f1;
        if (ks < 4) {
            f0 = *(const floatx4*)(px + ks * 32);
            f1 = *(const floatx4*)(px + ks * 32 + 4);
        } else {
            const float* sa = &agg[li][(ks - 4) * 32 + h * 8];
            f0 = *(const floatx4*)(sa);
            f1 = *(const floatx4*)(sa + 4);
            f0 *= rcn;
            f1 *= rcn;
        }
        bf16x8 a;
#pragma unroll
        for (int j = 0; j < 4; ++j) {
            a[j] = (bf16_t)f0[j];
            a[j + 4] = (bf16_t)f1[j];
        }
        acc0 = MFMA(a, bfr2[0][ks], acc0);
        acc1 = MFMA(a, bfr2[1][ks], acc1);
    }
#pragma unroll
    for (int r = 0; r < 4; ++r) {
        long ir = v0 + h * 4 + r;
        out[ir * GNN_H + n0 + li] = fmaxf(acc0[r] + nb0, 0.f);
        out[ir * GNN_H + n0 + 16 + li] = fmaxf(acc1[r] + nb1, 0.f);
    }
}

// v6 fused: 3-set round-robin pipeline, no register rotation, no shuffles.
__global__ __launch_bounds__(256) void fused_v6(
    const float* __restrict__ x, const float* __restrict__ ea,
    const float* __restrict__ b1, const float* __restrict__ b2,
    const char* __restrict__ ws, float* __restrict__ out) {
    const bf16_t* w1ct = (const bf16_t*)(ws + OFF_W1CT);
    const bf16_t* rc = (const bf16_t*)(ws + OFF_RC);
    const int* rowptr = (const int*)(ws + OFF_RP);
    const unsigned* pk32 = (const unsigned*)(ws + OFF_PERM);
    const unsigned* eidx = (const unsigned*)(ws + OFF_EIDX);

    __shared__ float agg[NB][132];
    __shared__ float cl[NB][132];

    int lane = threadIdx.x & 63;
    int w = threadIdx.x >> 6;
    int li = lane & 15;
    int h = lane >> 4;
    int n0 = w * 32;
    int v0 = blockIdx.x * NB;

    for (int i = threadIdx.x; i < NB * 132; i += 256) ((float*)agg)[i] = 0.f;
    {   // stage cl = C-part + b1 (bias folded in)
        int j = threadIdx.x >> 4;
        int c0 = (threadIdx.x & 15) * 8;
        bf16x8 v = *(const bf16x8*)(rc + (long)(v0 + j) * 256 + 128 + c0);
#pragma unroll
        for (int q = 0; q < 8; ++q) cl[j][c0 + q] = (float)v[q] + b1[c0 + q];
    }

    bf16x8 bc00 = *(const bf16x8*)(w1ct + (n0 + li) * 64 + h * 8);
    bf16x8 bc01 = *(const bf16x8*)(w1ct + (n0 + li) * 64 + 32 + h * 8);
    bf16x8 bc10 = *(const bf16x8*)(w1ct + (n0 + 16 + li) * 64 + h * 8);
    bf16x8 bc11 = *(const bf16x8*)(w1ct + (n0 + 16 + li) * 64 + 32 + h * 8);

    int e_beg = rowptr[v0];
    int e_end = rowptr[v0 + NB];
    __syncthreads();

    if (e_beg < e_end) {
        const int ntile = (e_end - e_beg + 15) >> 4;
        const int h4 = h * 4;

#define CP(p) ((p) < e_end ? (p) : e_end - 1)
#define DECL_SET(S)                                                        \
    unsigned pke##S, pk##S##0, pk##S##1, pk##S##2, pk##S##3;               \
    floatx4 ea##S##0, ea##S##1, ea##S##2, ea##S##3;                        \
    bf16_t R##S##0, R##S##1, R##S##2, R##S##3, R##S##4, R##S##5, R##S##6,  \
        R##S##7;                                                           \
    int nl##S##0, nl##S##1, nl##S##2, nl##S##3;
#define LOAD_PK(S, T)                                                      \
    do {                                                                   \
        int bb_ = e_beg + ((T) << 4);                                      \
        pke##S = eidx[CP(bb_ + li)];                                       \
        pk##S##0 = pk32[CP(bb_ + h4)];                                     \
        pk##S##1 = pk32[CP(bb_ + h4 + 1)];                                 \
        pk##S##2 = pk32[CP(bb_ + h4 + 2)];                                 \
        pk##S##3 = pk32[CP(bb_ + h4 + 3)];                                 \
    } while (0)
#define ISSUE_DATA(S)                                                      \
    do {                                                                   \
        const float* pe_ = ea + (size_t)pke##S * EDGE_H + h * 8;           \
        ea##S##0 = *(const floatx4*)pe_;                                   \
        ea##S##1 = *(const floatx4*)(pe_ + 4);                             \
        ea##S##2 = *(const floatx4*)(pe_ + 32);                            \
        ea##S##3 = *(const floatx4*)(pe_ + 36);                            \
        {                                                                  \
            const bf16_t* p_ = rc + (size_t)(pk##S##0 & 0x1FFFFu) * 256 +  \
                               n0 + li;                                    \
            R##S##0 = p_[0]; R##S##4 = p_[16];                             \
        }                                                                  \
        {                                                                  \
            const bf16_t* p_ = rc + (size_t)(pk##S##1 & 0x1FFFFu) * 256 +  \
                               n0 + li;                                    \
            R##S##1 = p_[0]; R##S##5 = p_[16];                             \
        }                                                                  \
        {                                                                  \
            const bf16_t* p_ = rc + (size_t)(pk##S##2 & 0x1FFFFu) * 256 +  \
                               n0 + li;                                    \
            R##S##2 = p_[0]; R##S##6 = p_[16];                             \
        }                                                                  \
        {                                                                  \
            const bf16_t* p_ = rc + (size_t)(pk##S##3 & 0x1FFFFu) * 256 +  \
                               n0 + li;                                    \
            R##S##3 = p_[0]; R##S##7 = p_[16];                             \
        }                                                                  \
        nl##S##0 = (int)((pk##S##0 >> 17) & 15u);                          \
        nl##S##1 = (int)((pk##S##1 >> 17) & 15u);                          \
        nl##S##2 = (int)((pk##S##2 >> 17) & 15u);                          \
        nl##S##3 = (int)((pk##S##3 >> 17) & 15u);                          \
    } while (0)
#define COMPUTE(S, T)                                                      \
    do {                                                                   \
        bf16x8 a0_, a1_;                                                   \
        _Pragma("unroll") for (int j_ = 0; j_ < 4; ++j_) {                 \
            a0_[j_] = (bf16_t)ea##S##0[j_];                                \
            a0_[j_ + 4] = (bf16_t)ea##S##1[j_];                            \
            a1_[j_] = (bf16_t)ea##S##2[j_];                                \
            a1_[j_ + 4] = (bf16_t)ea##S##3[j_];                            \
        }                                                                  \
        floatx4 ac0_ = {0.f, 0.f, 0.f, 0.f};                               \
        floatx4 ac1_ = {0.f, 0.f, 0.f, 0.f};                               \
        ac0_ = MFMA(a0_, bc00, ac0_);                                      \
        ac0_ = MFMA(a1_, bc01, ac0_);                                      \
        ac1_ = MFMA(a0_, bc10, ac1_);                                      \
        ac1_ = MFMA(a1_, bc11, ac1_);                                      \
        int base_ = e_beg + ((T) << 4);                                    \
        float m00_ = fmaxf(ac0_[0] + (float)R##S##0 + cl[nl##S##0][n0 + li], 0.f); \
        float m01_ = fmaxf(ac0_[1] + (float)R##S##1 + cl[nl##S##1][n0 + li], 0.f); \
        float m02_ = fmaxf(ac0_[2] + (float)R##S##2 + cl[nl##S##2][n0 + li], 0.f); \
        float m03_ = fmaxf(ac0_[3] + (float)R##S##3 + cl[nl##S##3][n0 + li], 0.f); \
        float m10_ = fmaxf(ac1_[0] + (float)R##S##4 + cl[nl##S##0][n0 + 16 + li], 0.f); \
        float m11_ = fmaxf(ac1_[1] + (float)R##S##5 + cl[nl##S##1][n0 + 16 + li], 0.f); \
        float m12_ = fmaxf(ac1_[2] + (float)R##S##6 + cl[nl##S##2][n0 + 16 + li], 0.f); \
        float m13_ = fmaxf(ac1_[3] + (float)R##S##7 + cl[nl##S##3][n0 + 16 + li], 0.f); \
        if ((base_ + h4 + 3) < e_end && nl##S##0 == nl##S##1 &&            \
            nl##S##1 == nl##S##2 && nl##S##2 == nl##S##3) {                \
            atomicAdd(&agg[nl##S##0][n0 + li], m00_ + m01_ + m02_ + m03_); \
            atomicAdd(&agg[nl##S##0][n0 + 16 + li], m10_ + m11_ + m12_ + m13_); \
        } else {                                                           \
            if (base_ + h4 < e_end) {                                      \
                atomicAdd(&agg[nl##S##0][n0 + li], m00_);                  \
                atomicAdd(&agg[nl##S##0][n0 + 16 + li], m10_);             \
            }                                                              \
            if (base_ + h4 + 1 < e_end) {                                  \
                atomicAdd(&agg[nl##S##1][n0 + li], m01_);                  \
                atomicAdd(&agg[nl##S##1][n0 + 16 + li], m11_);             \
            }                                                              \
            if (base_ + h4 + 2 < e_end) {                                  \
                atomicAdd(&agg[nl##S##2][n0 + li], m02_);                  \
                atomicAdd(&agg[nl##S##2][n0 + 16 + li], m12_);             \
            }                                                              \
            if (base_ + h4 + 3 < e_end) {                                  \
                atomicAdd(&agg[nl##S##3][n0 + li], m03_);                  \
                atomicAdd(&agg[nl##S##3][n0 + 16 + li], m13_);             \
            }                                                              \
        }                                                                  \
    } while (0)

        DECL_SET(A)
        DECL_SET(B)
        DECL_SET(C)

        // prologue: fill data sets for tiles 0..2; pk sets advance to 3..5
        LOAD_PK(A, 0);
        LOAD_PK(B, 1);
        LOAD_PK(C, 2);
        ISSUE_DATA(A);
        LOAD_PK(A, 3);
        ISSUE_DATA(B);
        LOAD_PK(B, 4);
        ISSUE_DATA(C);
        LOAD_PK(C, 5);

        int t = 0;
        for (; t + 3 <= ntile; t += 3) {
            COMPUTE(A, t);
            ISSUE_DATA(A);
            LOAD_PK(A, t + 6);
            COMPUTE(B, t + 1);
            ISSUE_DATA(B);
            LOAD_PK(B, t + 7);
            COMPUTE(C, t + 2);
            ISSUE_DATA(C);
            LOAD_PK(C, t + 8);
        }
        if (t < ntile) COMPUTE(A, t);
        if (t + 1 < ntile) COMPUTE(B, t + 1);
#undef CP
    }
    __syncthreads();
    node_mlp(x, b2, ws, agg, rowptr, out, v0, li, h, n0);
}

// ======================= v1 fallback (tiny ws) =======================

__global__ void prep_kernel(const float* __restrict__ W1, const float* __restrict__ W2,
                            const int* __restrict__ ei32, char* __restrict__ ws) {
    bf16_t* w1t = (bf16_t*)(ws + OFF_W1T);
    bf16_t* w2t = (bf16_t*)(ws + OFF_W2T);
    int tid = blockIdx.x * blockDim.x + threadIdx.x;
    int nt = gridDim.x * blockDim.x;
    for (int i = tid; i < K1 * GNN_H; i += nt) {
        int n = i / K1, k = i - n * K1;
        w1t[i] = (bf16_t)W1[k * GNN_H + n];
    }
    for (int i = tid; i < K2 * GNN_H; i += nt) {
        int n = i / K2, k = i - n * K2;
        w2t[i] = (bf16_t)W2[k * GNN_H + n];
    }
    if (blockIdx.x == 0) {
        __shared__ int any_nonzero;
        if (threadIdx.x == 0) any_nonzero = 0;
        __syncthreads();
        if (ei32[2 * threadIdx.x + 1] != 0) atomicOr(&any_nonzero, 1);
        __syncthreads();
        if (threadIdx.x == 0) *(int*)(ws + OFF_FLAG) = (any_nonzero == 0) ? 1 : 0;
    }
}

__global__ void count_kernel(const void* __restrict__ ei, const char* __restrict__ ws,
                             float* __restrict__ cnt) {
    int is64 = *(const int*)(ws + OFF_FLAG);
    int e = blockIdx.x * blockDim.x + threadIdx.x;
    if (e < E_EDGES) {
        long c = load_idx(ei, is64, (long)E_EDGES + e);
        atomicAdd(cnt + c, 1.0f);
    }
}

__global__ __launch_bounds__(256) void edge_kernel(
    const float* __restrict__ x, const void* __restrict__ ei,
    const float* __restrict__ ea, const float* __restrict__ b1,
    const char* __restrict__ ws, float* __restrict__ s) {
    const bf16_t* w1t = (const bf16_t*)(ws + OFF_W1T);
    int is64 = *(const int*)(ws + OFF_FLAG);
    int lane = threadIdx.x & 63;
    int w = threadIdx.x >> 6;
    int li = lane & 15;
    int h = lane >> 4;
    int n0 = w * 32;

    bf16x8 bf[2][10];
#pragma unroll
    for (int t = 0; t < 2; ++t)
#pragma unroll
        for (int ks = 0; ks < 10; ++ks)
            bf[t][ks] = *(const bf16x8*)(w1t + (long)(n0 + t * 16 + li) * K1 + ks * 32 + h * 8);
    float bias0 = b1[n0 + li];
    float bias1 = b1[n0 + 16 + li];

    const int ntiles = E_EDGES / 16;
    for (int tile = blockIdx.x; tile < ntiles; tile += gridDim.x) {
        int m0 = tile * 16;
        int e = m0 + li;
        long rowi = load_idx(ei, is64, e);
        long coli = load_idx(ei, is64, (long)E_EDGES + e);
        const float* pr = x + rowi * NODE_H + h * 8;
        const float* pc = x + coli * NODE_H + h * 8;
        const float* pe = ea + (long)e * EDGE_H + h * 8;
        floatx4 acc0 = {0.f, 0.f, 0.f, 0.f};
        floatx4 acc1 = {0.f, 0.f, 0.f, 0.f};
#pragma unroll
        for (int ks = 0; ks < 10; ++ks) {
            const float* src = (ks < 4) ? (pr + ks * 32) : (ks < 8) ? (pc + (ks - 4) * 32)
                                                                    : (pe + (ks - 8) * 32);
            floatx4 f0 = *(const floatx4*)(src);
            floatx4 f1 = *(const floatx4*)(src + 4);
            bf16x8 a;
#pragma unroll
            for (int j = 0; j < 4; ++j) {
                a[j] = (bf16_t)f0[j];
                a[j + 4] = (bf16_t)f1[j];
            }
            acc0 = MFMA(a, bf[0][ks], acc0);
            acc1 = MFMA(a, bf[1][ks], acc1);
        }
        long cols[4];
#pragma unroll
        for (int r = 0; r < 4; ++r)
            cols[r] = load_idx(ei, is64, (long)E_EDGES + m0 + h * 4 + r);
#pragma unroll
        for (int r = 0; r < 4; ++r) {
            float v0 = fmaxf(acc0[r] + bias0, 0.f);
            float v1 = fmaxf(acc1[r] + bias1, 0.f);
            atomicAdd(s + cols[r] * GNN_H + n0 + li, v0);
            atomicAdd(s + cols[r] * GNN_H + n0 + 16 + li, v1);
        }
    }
}

__global__ __launch_bounds__(256) void node_kernel(
    const float* __restrict__ x, const float* __restrict__ b2,
    const char* __restrict__ ws, const float* __restrict__ cnt,
    const float* __restrict__ s, float* __restrict__ out) {
    const bf16_t* w2t = (const bf16_t*)(ws + OFF_W2T);
    int lane = threadIdx.x & 63;
    int w = threadIdx.x >> 6;
    int li = lane & 15;
    int h = lane >> 4;
    int n0 = w * 32;

    bf16x8 bf[2][8];
#pragma unroll
    for (int t = 0; t < 2; ++t)
#pragma unroll
        for (int ks = 0; ks < 8; ++ks)
            bf[t][ks] = *(const bf16x8*)(w2t + (long)(n0 + t * 16 + li) * K2 + ks * 32 + h * 8);
    float bias0 = b2[n0 + li];
    float bias1 = b2[n0 + 16 + li];

    int m0 = blockIdx.x * 16;
    int i = m0 + li;
    float rcn = 1.0f / fmaxf(cnt[i], 1.0f);
    const float* px = x + (long)i * NODE_H + h * 8;
    const float* ps = s + (long)i * GNN_H + h * 8;
    floatx4 acc0 = {0.f, 0.f, 0.f, 0.f};
    floatx4 acc1 = {0.f, 0.f, 0.f, 0.f};
#pragma unroll
    for (int ks = 0; ks < 8; ++ks) {
        const float* src = (ks < 4) ? (px + ks * 32) : (ps + (ks - 4) * 32);
        floatx4 f0 = *(const floatx4*)(src);
        floatx4 f1 = *(const floatx4*)(src + 4);
        if (ks >= 4) {
            f0 *= rcn;
            f1 *= rcn;
        }
        bf16x8 a;
#pragma unroll
        for (int j = 0; j < 4; ++j) {
            a[j] = (bf16_t)f0[j];
            a[j + 4] = (bf16_t)f1[j];
        }
        acc0 = MFMA(a, bf[0][ks], acc0);
        acc1 = MFMA(a, bf[1][ks], acc1);
    }
    __syncthreads();  // s == out in-place: all reads done before stores
#pragma unroll
    for (int r = 0; r < 4; ++r) {
        long ir = m0 + h * 4 + r;
        out[ir * GNN_H + n0 + li] = fmaxf(acc0[r] + bias0, 0.f);
        out[ir * GNN_H + n0 + 16 + li] = fmaxf(acc1[r] + bias1, 0.f);
    }
}

extern "C" void kernel_launch(void* const* d_in, const int* in_sizes, int n_in,
                              void* d_out, int out_size, void* d_ws, size_t ws_size,
                              hipStream_t stream) {
    const float* x = (const float*)d_in[0];
    const void* ei = d_in[1];
    const float* ea = (const float*)d_in[2];
    const float* W1 = (const float*)d_in[3];
    const float* b1 = (const float*)d_in[4];
    const float* W2 = (const float*)d_in[5];
    const float* b2 = (const float*)d_in[6];
    float* out = (float*)d_out;
    char* ws = (char*)d_ws;

    if (ws_size >= WS_V6) {
        int* cnt = (int*)(ws + OFF_CNT);
        hipMemsetAsync(cnt, 0, NN * 4, stream);
        prep_hist<<<2048, 256, 0, stream>>>(W1, W2, (const int*)ei, ws, cnt);
        scan_kernel<<<1, 1024, 0, stream>>>(cnt, (int*)(ws + OFF_RP), (int*)(ws + OFF_WOFF));
        scatrc_kernel<<<E_EDGES / 256 + NN / 16, 256, 0, stream>>>(
            (const int*)ei, x, ws, (int*)(ws + OFF_WOFF));
        fused_v6<<<NN / NB, 256, 0, stream>>>(x, ea, b1, b2, ws, out);
    } else {
        prep_kernel<<<32, 256, 0, stream>>>(W1, W2, (const int*)ei, ws);
        float* cntf = (float*)(ws + OFF_CNT);
        hipMemsetAsync(cntf, 0, NN * 4, stream);
        hipMemsetAsync(out, 0, (size_t)NN * GNN_H * 4, stream);
        count_kernel<<<E_EDGES / 256, 256, 0, stream>>>(ei, ws, cntf);
        edge_kernel<<<4096, 256, 0, stream>>>(x, ei, ea, b1, ws, out);
        node_kernel<<<NN / 16, 256, 0, stream>>>(x, b2, ws, cntf, out, out);
    }
}